// Round 16
// baseline (184.490 us; speedup 1.0000x reference)
//
#include <hip/hip_runtime.h>
#include <math.h>

static __device__ __forceinline__ float lrelu(float x){ return x > 0.f ? x : 0.01f * x; }

// ---- workspace layout (float offsets) ----
#define OFF_XE    196608
#define OFF_XA    294912
#define OFF_QKVE  393216
#define OFF_QKVA  688128
#define OFF_AOP   983040    // 4 splits * 768*128
#define OFF_DEN   1376256   // 4 splits * 768*4
#define OFF_AOA   1388544   // 15*96*128
#define OFF_QVE   1572864
#define OFF_QVA   1573632
#define WS_FLOATS 1575072

// ---- output layout (fp32 elems) ----
#define OUT_POL 0
#define OUT_QV  24576
#define OUT_EO  25344

#define SCALE_ATTN 0.17677669529663689f  // 1/sqrt(32)

// Runtime-looped chunked dot, 2 rows: one 8-float4 weight chunk live at a
// time (#pragma unroll 1 defeats load hoisting — r13/r14 spill lesson).
template<int NCHUNK>
static __device__ __forceinline__ void phase_dot2(
    const float* __restrict__ wbase,
    const float* __restrict__ x0, const float* __restrict__ x1,
    float* __restrict__ accs)
{
  #pragma unroll 1
  for (int ch = 0; ch < NCHUNK; ++ch) {
    const float4* wp = (const float4*)(wbase + ch * 32);
    float4 wf[8];
    #pragma unroll
    for (int i = 0; i < 8; ++i) wf[i] = wp[i];
    const float* xr0 = x0 + ch * 32;
    const float* xr1 = x1 + ch * 32;
    #pragma unroll
    for (int r = 0; r < 2; ++r) {
      const float* xr = (r == 0) ? xr0 : xr1;
      float ax = 0.f, ay = 0.f, az = 0.f, aw = 0.f;
      #pragma unroll
      for (int i = 0; i < 8; ++i) {
        float4 x = *(const float4*)&xr[i * 4];
        ax = fmaf(x.x, wf[i].x, ax); ay = fmaf(x.y, wf[i].y, ay);
        az = fmaf(x.z, wf[i].z, az); aw = fmaf(x.w, wf[i].w, aw);
      }
      accs[r] += (ax + ay) + (az + aw);
    }
  }
}

static __device__ __forceinline__ void tail_mac4_2(const float4* __restrict__ wp,
    const float* __restrict__ x0, const float* __restrict__ x1,
    float* __restrict__ accs)
{
  float4 wf[4];
  #pragma unroll
  for (int i = 0; i < 4; ++i) wf[i] = wp[i];
  #pragma unroll
  for (int r = 0; r < 2; ++r) {
    const float* xr = (r == 0) ? x0 : x1;
    float ax = 0.f, ay = 0.f, az = 0.f, aw = 0.f;
    #pragma unroll
    for (int i = 0; i < 4; ++i) {
      float4 x = *(const float4*)&xr[i * 4];
      ax = fmaf(x.x, wf[i].x, ax); ay = fmaf(x.y, wf[i].y, ay);
      az = fmaf(x.z, wf[i].z, az); aw = fmaf(x.w, wf[i].w, aw);
    }
    accs[r] += (ax + ay) + (az + aw);
  }
}

// ================================================================
// K12ws v5: weight-stationary front end, 2 rows/block, grid 768
// (3 blocks/CU vs r15's 1.5 — phases overlap across blocks).
// Blocks 0..383   (E): obs -> eo -> x_e -> qkv_e
// Blocks 384..767 (A): obs -> L1 -> L2 -> L3/pol -> ea -> x_a -> qkv_a
// Thread (c = (t&31)|((t>>6)<<5), h = (t>>5)&1); __shfl_xor(32) combine.
// ================================================================
__global__ __launch_bounds__(256) void k12ws_front(
    const float* __restrict__ obs,
    const float* __restrict__ aw1, const float* __restrict__ ab1,
    const float* __restrict__ aw2, const float* __restrict__ ab2,
    const float* __restrict__ aw3, const float* __restrict__ ab3,
    const float* __restrict__ eow, const float* __restrict__ eob,
    const float* __restrict__ eaw, const float* __restrict__ eab,
    const float* __restrict__ riw, const float* __restrict__ rib,
    const float* __restrict__ miw, const float* __restrict__ mib,
    float* __restrict__ out, float* __restrict__ ws)
{
  __shared__ float sA[2][256];   // A: h1, then ea in [0..128)  | E: eo
  __shared__ float sB[2][160];   // A: [obs | pol]              | E: obs
  __shared__ float sC[2][128];   // A: h2, then x_a             | E: x_e
  const int t  = threadIdx.x;
  const int bx = blockIdx.x;
  const bool isE = (bx < 384);
  const int r0 = (isE ? bx : bx - 384) * 2;

  const int c = (t & 31) | ((t >> 6) << 5);   // out-col 0..127
  const int h = (t >> 5) & 1;                 // k-half

  for (int s = t; s < 256; s += 256) {
    int ri = s >> 7, k = s & 127;
    sB[ri][k] = obs[(r0 + ri) * 128 + k];
  }
  __syncthreads();

  if (isE) {
    { // ---- eo ----
      float accs[2] = {0.f, 0.f};
      phase_dot2<2>(eow + c * 128 + h * 64, &sB[0][h*64], &sB[1][h*64], accs);
      const float bias = eob[c];
      #pragma unroll
      for (int r = 0; r < 2; ++r) {
        float acc = accs[r];
        acc += __shfl_xor(acc, 32);
        if (h == 0) {
          float v = acc + bias;
          sA[r][c] = v;
          out[OUT_EO + (r0 + r) * 128 + c] = v;
        }
      }
    }
    __syncthreads();
    { // ---- x_e ----
      float accs[2] = {0.f, 0.f};
      phase_dot2<2>(riw + c * 128 + h * 64, &sA[0][h*64], &sA[1][h*64], accs);
      const float bias = rib[c];
      #pragma unroll
      for (int r = 0; r < 2; ++r) {
        float acc = accs[r];
        acc += __shfl_xor(acc, 32);
        if (h == 0) {
          float v = fmaxf(acc + bias, 0.f);
          sC[r][c] = v;
          ws[OFF_XE + (r0 + r) * 128 + c] = v;
        }
      }
    }
    __syncthreads();
    // ---- qkv_e (3 col-groups) ----
    #pragma unroll 1
    for (int g = 0; g < 3; ++g) {
      float accs[2] = {0.f, 0.f};
      phase_dot2<2>(miw + (size_t)(g * 128 + c) * 128 + h * 64,
                    &sC[0][h*64], &sC[1][h*64], accs);
      const float bias = mib[g * 128 + c];
      #pragma unroll
      for (int r = 0; r < 2; ++r) {
        float acc = accs[r];
        acc += __shfl_xor(acc, 32);
        if (h == 0)
          ws[OFF_QKVE + (size_t)(r0 + r) * 384 + g * 128 + c] = acc + bias;
      }
    }
  } else {
    // ---- L1 (2 col-groups) ----
    #pragma unroll 1
    for (int g = 0; g < 2; ++g) {
      float accs[2] = {0.f, 0.f};
      phase_dot2<2>(aw1 + (size_t)(g * 128 + c) * 128 + h * 64,
                    &sB[0][h*64], &sB[1][h*64], accs);
      const float bias = ab1[g * 128 + c];
      #pragma unroll
      for (int r = 0; r < 2; ++r) {
        float acc = accs[r];
        acc += __shfl_xor(acc, 32);
        if (h == 0) sA[r][g * 128 + c] = lrelu(acc + bias);
      }
    }
    __syncthreads();
    { // ---- L2 (K=256: two 128-halves) ----
      float accs[2] = {0.f, 0.f};
      phase_dot2<2>(aw2 + (size_t)c * 256 + h * 64,
                    &sA[0][h*64], &sA[1][h*64], accs);
      phase_dot2<2>(aw2 + (size_t)c * 256 + 128 + h * 64,
                    &sA[0][128+h*64], &sA[1][128+h*64], accs);
      const float bias = ab2[c];
      #pragma unroll
      for (int r = 0; r < 2; ++r) {
        float acc = accs[r];
        acc += __shfl_xor(acc, 32);
        if (h == 0) sC[r][c] = lrelu(acc + bias);
      }
    }
    __syncthreads();
    // ---- L3 + GELU (wave 0 only) ----
    if (t < 64) {
      const int c2 = t & 31, h2 = t >> 5;
      float accs[2] = {0.f, 0.f};
      phase_dot2<2>(aw3 + (size_t)c2 * 128 + h2 * 64,
                    &sC[0][h2*64], &sC[1][h2*64], accs);
      const float bias = ab3[c2];
      #pragma unroll
      for (int r = 0; r < 2; ++r) {
        float acc = accs[r];
        acc += __shfl_xor(acc, 32);
        if (h2 == 0) {
          float a = acc + bias;
          float g = 0.5f * a * (1.f + erff(a * 0.70710678118654752f));
          sB[r][128 + c2] = g;
          out[OUT_POL + (r0 + r) * 32 + c2] = g;
        }
      }
    }
    __syncthreads();
    { // ---- ea (K=160: halves of 80 = 2 chunks + tail) ----
      float accs[2] = {0.f, 0.f};
      const float* wb = eaw + (size_t)c * 160 + h * 80;
      phase_dot2<2>(wb, &sB[0][h*80], &sB[1][h*80], accs);
      tail_mac4_2((const float4*)(wb + 64), &sB[0][h*80+64], &sB[1][h*80+64], accs);
      const float bias = eab[c];
      #pragma unroll
      for (int r = 0; r < 2; ++r) {
        float acc = accs[r];
        acc += __shfl_xor(acc, 32);
        if (h == 0) sA[r][c] = acc + bias;
      }
    }
    __syncthreads();
    { // ---- x_a ----
      float accs[2] = {0.f, 0.f};
      phase_dot2<2>(riw + c * 128 + h * 64, &sA[0][h*64], &sA[1][h*64], accs);
      const float bias = rib[c];
      #pragma unroll
      for (int r = 0; r < 2; ++r) {
        float acc = accs[r];
        acc += __shfl_xor(acc, 32);
        if (h == 0) {
          float v = fmaxf(acc + bias, 0.f);
          sC[r][c] = v;
          ws[OFF_XA + (r0 + r) * 128 + c] = v;
        }
      }
    }
    __syncthreads();
    // ---- qkv_a (3 col-groups) ----
    #pragma unroll 1
    for (int g = 0; g < 3; ++g) {
      float accs[2] = {0.f, 0.f};
      phase_dot2<2>(miw + (size_t)(g * 128 + c) * 128 + h * 64,
                    &sC[0][h*64], &sC[1][h*64], accs);
      const float bias = mib[g * 128 + c];
      #pragma unroll
      for (int r = 0; r < 2; ++r) {
        float acc = accs[r];
        acc += __shfl_xor(acc, 32);
        if (h == 0)
          ws[OFF_QKVA + (size_t)(r0 + r) * 384 + g * 128 + c] = acc + bias;
      }
    }
  }
}

// ================================================================
// K356: fused attention (unchanged).
// ================================================================
__global__ __launch_bounds__(256) void k356_attn(float* __restrict__ ws)
{
  __shared__ __align__(16) union {
    struct { float Qs[16 * 36]; float KsT[32 * 68]; float VsT[32 * 68]; float Ss[16 * 68]; } e;
    struct { float Qb[48 * 33]; float Ka[96 * 33]; float Va[96 * 36]; float Ss[48 * 97]; float rinv[48]; } a;
  } su;
  const int t  = threadIdx.x;
  const int bx = blockIdx.x;

  if (bx < 768) {
    const int l0 = (bx % 48) * 16, h = (bx / 48) & 3, sp = bx / 192;
    const float* qkve = ws + OFF_QKVE;

    for (int f = t; f < 512; f += 256)
      su.e.Qs[(f >> 5) * 36 + (f & 31)] = qkve[(size_t)(l0 + (f >> 5)) * 384 + h * 32 + (f & 31)];
    __syncthreads();

    const int l = t >> 4, j = t & 15, c0 = j * 4;
    float q[32];
    #pragma unroll
    for (int dd = 0; dd < 8; ++dd) {
      float4 qq = *(const float4*)&su.e.Qs[l * 36 + dd * 4];
      q[dd*4+0] = qq.x; q[dd*4+1] = qq.y; q[dd*4+2] = qq.z; q[dd*4+3] = qq.w;
    }
    float o0 = 0.f, o1 = 0.f, dsum = 0.f;

    for (int mt = sp * 3; mt < sp * 3 + 3; ++mt) {
      const int m0 = mt * 64;
      __syncthreads();
      for (int f = t; f < 2048; f += 256) {
        int i = f >> 5, d = f & 31;
        const float* src = qkve + (size_t)(m0 + i) * 384 + h * 32 + d;
        su.e.KsT[d * 68 + i] = src[128];
        su.e.VsT[d * 68 + i] = src[256];
      }
      __syncthreads();

      float s0 = 0.f, s1 = 0.f, s2 = 0.f, s3 = 0.f;
      #pragma unroll
      for (int d = 0; d < 32; ++d) {
        float4 kk = *(const float4*)&su.e.KsT[d * 68 + c0];
        s0 = fmaf(q[d], kk.x, s0); s1 = fmaf(q[d], kk.y, s1);
        s2 = fmaf(q[d], kk.z, s2); s3 = fmaf(q[d], kk.w, s3);
      }
      s0 = expf(s0 * SCALE_ATTN); s1 = expf(s1 * SCALE_ATTN);
      s2 = expf(s2 * SCALE_ATTN); s3 = expf(s3 * SCALE_ATTN);
      float4 sv; sv.x = s0; sv.y = s1; sv.z = s2; sv.w = s3;
      *(float4*)&su.e.Ss[l * 68 + c0] = sv;
      float psum = (s0 + s1) + (s2 + s3);
      psum += __shfl_xor(psum, 1); psum += __shfl_xor(psum, 2);
      psum += __shfl_xor(psum, 4); psum += __shfl_xor(psum, 8);
      dsum += psum;

      float t0x=0.f,t0y=0.f,t0z=0.f,t0w=0.f, t1x=0.f,t1y=0.f,t1z=0.f,t1w=0.f;
      #pragma unroll
      for (int k4 = 0; k4 < 16; ++k4) {
        float4 p  = *(const float4*)&su.e.Ss[l * 68 + k4 * 4];
        float4 va = *(const float4*)&su.e.VsT[j * 68 + k4 * 4];
        float4 vb = *(const float4*)&su.e.VsT[(j + 16) * 68 + k4 * 4];
        t0x = fmaf(p.x, va.x, t0x); t0y = fmaf(p.y, va.y, t0y);
        t0z = fmaf(p.z, va.z, t0z); t0w = fmaf(p.w, va.w, t0w);
        t1x = fmaf(p.x, vb.x, t1x); t1y = fmaf(p.y, vb.y, t1y);
        t1z = fmaf(p.z, vb.z, t1z); t1w = fmaf(p.w, vb.w, t1w);
      }
      o0 += (t0x + t0y) + (t0z + t0w);
      o1 += (t1x + t1y) + (t1z + t1w);
    }

    float* aop = ws + OFF_AOP + (size_t)sp * 98304;
    aop[(size_t)(l0 + l) * 128 + h * 32 + j]      = o0;
    aop[(size_t)(l0 + l) * 128 + h * 32 + j + 16] = o1;
    if (j == 0) ws[OFF_DEN + sp * 3072 + (l0 + l) * 4 + h] = dsum;
  } else {
    const int z  = bx - 768;
    const int j1 = z >> 3;
    const int h  = (z & 7) >> 1, rb = z & 1;
    const int jj = j1 + 1;
    const float* qkva = ws + OFF_QKVA;

    for (int f = t; f < 3072; f += 256) {
      int ml = f >> 5, d = f & 31;
      int bp = ml >> 1, spar = ml & 1;
      int ag = spar ? jj : (jj - 1);
      const float* src = qkva + (size_t)(bp * 16 + ag) * 384 + h * 32 + d;
      su.a.Ka[ml * 33 + d] = src[128];
      su.a.Va[ml * 36 + d] = src[256];
    }
    for (int f = t; f < 1536; f += 256) {
      int ql = f >> 5, d = f & 31;
      int Lb = rb * 48 + ql;
      int b = Lb >> 1, s = Lb & 1;
      int ag = s ? jj : (jj - 1);
      su.a.Qb[ql * 33 + d] = qkva[(size_t)(b * 16 + ag) * 384 + h * 32 + d];
    }
    __syncthreads();

    {
      const int tl = (t >> 4) * 3, tm = (t & 15) * 6;
      float acc[3][6] = {{0.f}};
      #pragma unroll
      for (int d = 0; d < 32; ++d) {
        float qv[3], kv[6];
        #pragma unroll
        for (int r = 0; r < 3; ++r) qv[r] = su.a.Qb[(tl + r) * 33 + d];
        #pragma unroll
        for (int c = 0; c < 6; ++c) kv[c] = su.a.Ka[(tm + c) * 33 + d];
        #pragma unroll
        for (int r = 0; r < 3; ++r)
          #pragma unroll
          for (int c = 0; c < 6; ++c) acc[r][c] = fmaf(qv[r], kv[c], acc[r][c]);
      }
      const float wj = (float)jj, wnj = (float)(16 - jj);
      float rs[3] = {0.f, 0.f, 0.f};
      #pragma unroll
      for (int r = 0; r < 3; ++r)
        #pragma unroll
        for (int c = 0; c < 6; ++c) {
          float w = ((tm + c) & 1) ? wj : wnj;
          float p = w * expf(acc[r][c] * SCALE_ATTN);
          su.a.Ss[(tl + r) * 97 + tm + c] = p;
          rs[r] += p;
        }
      #pragma unroll
      for (int r = 0; r < 3; ++r) {
        rs[r] += __shfl_xor(rs[r], 1); rs[r] += __shfl_xor(rs[r], 2);
        rs[r] += __shfl_xor(rs[r], 4); rs[r] += __shfl_xor(rs[r], 8);
      }
      if ((t & 15) == 0) {
        su.a.rinv[tl + 0] = 1.f / rs[0];
        su.a.rinv[tl + 1] = 1.f / rs[1];
        su.a.rinv[tl + 2] = 1.f / rs[2];
      }
    }
    __syncthreads();

    if (t < 192) {
      const int l0 = (t >> 3) * 2, d0 = (t & 7) * 4;
      float a0x=0.f,a0y=0.f,a0z=0.f,a0w=0.f, a1x=0.f,a1y=0.f,a1z=0.f,a1w=0.f;
      for (int m = 0; m < 96; ++m) {
        float p0 = su.a.Ss[l0 * 97 + m], p1 = su.a.Ss[(l0 + 1) * 97 + m];
        float4 v = *(const float4*)&su.a.Va[m * 36 + d0];
        a0x = fmaf(p0, v.x, a0x); a0y = fmaf(p0, v.y, a0y);
        a0z = fmaf(p0, v.z, a0z); a0w = fmaf(p0, v.w, a0w);
        a1x = fmaf(p1, v.x, a1x); a1y = fmaf(p1, v.y, a1y);
        a1z = fmaf(p1, v.z, a1z); a1w = fmaf(p1, v.w, a1w);
      }
      const float s0 = su.a.rinv[l0], s1 = su.a.rinv[l0 + 1];
      float* ao = ws + OFF_AOA + (size_t)(j1 * 96 + rb * 48 + l0) * 128 + h * 32 + d0;
      float4 o0; o0.x = a0x * s0; o0.y = a0y * s0; o0.z = a0z * s0; o0.w = a0w * s0;
      float4 o1; o1.x = a1x * s1; o1.y = a1y * s1; o1.z = a1z * s1; o1.w = a1w * s1;
      *(float4*)ao = o0;
      *(float4*)(ao + 128) = o1;
    }
  }
}

// ================================================================
// K7ab: merged epilogue. Per 8 ctx rows: ao (+k-split combine for e-rows)
// -> t1 in LDS -> ctx -> qv. No T1 global round-trip. grid=276.
// ================================================================
__global__ __launch_bounds__(256) void k7ab_epi(
    const float* __restrict__ mow, const float* __restrict__ mob,
    const float* __restrict__ roww, const float* __restrict__ robb,
    const float* __restrict__ qw,  const float* __restrict__ qb,
    float* __restrict__ ws)
{
  __shared__ float rows_in[8][132];
  __shared__ float res[8][132];
  __shared__ float t1s[8][132];
  __shared__ float qpart[8][4];
  const int t  = threadIdx.x;
  const int r0 = blockIdx.x * 8;

  for (int s = t; s < 1024; s += 256) {
    int ri = s >> 7, c = s & 127;
    int r = r0 + ri;
    float aoval, x1v;
    if (r < 768) {
      float num = ws[OFF_AOP + 0*98304 + (size_t)r*128 + c]
                + ws[OFF_AOP + 1*98304 + (size_t)r*128 + c]
                + ws[OFF_AOP + 2*98304 + (size_t)r*128 + c]
                + ws[OFF_AOP + 3*98304 + (size_t)r*128 + c];
      int hh = c >> 5;
      float den = ws[OFF_DEN + 0*3072 + r*4 + hh] + ws[OFF_DEN + 1*3072 + r*4 + hh]
                + ws[OFF_DEN + 2*3072 + r*4 + hh] + ws[OFF_DEN + 3*3072 + r*4 + hh];
      aoval = num / den;
      x1v = ws[OFF_XE + r*128 + c];
    } else {
      int rr = r - 768;
      aoval = ws[OFF_AOA + (size_t)rr*128 + c];
      int jx = rr / 96, l96 = rr % 96;
      int b = l96 >> 1, sa = l96 & 1;
      int ag = sa ? (jx + 1) : jx;
      x1v = ws[OFF_XA + (b*16 + ag)*128 + c];
    }
    rows_in[ri][c] = aoval;
    res[ri][c] = x1v;
  }

  const int c = (t & 31) | ((t >> 6) << 5);
  const int h = (t >> 5) & 1;
  __syncthreads();

  { // t1 phase (runtime-looped chunks, r15 spill lesson)
    float accs[8] = {0.f,0.f,0.f,0.f,0.f,0.f,0.f,0.f};
    const float* wb = mow + c * 128 + h * 64;
    #pragma unroll 1
    for (int ch = 0; ch < 2; ++ch) {
      const float4* wp = (const float4*)(wb + ch * 32);
      float4 wf[8];
      #pragma unroll
      for (int i = 0; i < 8; ++i) wf[i] = wp[i];
      #pragma unroll
      for (int ri = 0; ri < 8; ++ri) {
        const float* xr = &rows_in[ri][h * 64 + ch * 32];
        float ax = 0.f, ay = 0.f, az = 0.f, aw = 0.f;
        #pragma unroll
        for (int i = 0; i < 8; ++i) {
          float4 x = *(const float4*)&xr[i * 4];
          ax = fmaf(x.x, wf[i].x, ax); ay = fmaf(x.y, wf[i].y, ay);
          az = fmaf(x.z, wf[i].z, az); aw = fmaf(x.w, wf[i].w, aw);
        }
        accs[ri] += (ax + ay) + (az + aw);
      }
    }
    const float bias = mob[c];
    #pragma unroll
    for (int ri = 0; ri < 8; ++ri) {
      float acc = accs[ri];
      acc += __shfl_xor(acc, 32);
      if (h == 0) t1s[ri][c] = acc + bias + res[ri][c];
    }
  }
  __syncthreads();

  { // ctx + qv phase
    float accs[8] = {0.f,0.f,0.f,0.f,0.f,0.f,0.f,0.f};
    const float* wb = roww + c * 128 + h * 64;
    #pragma unroll 1
    for (int ch = 0; ch < 2; ++ch) {
      const float4* wp = (const float4*)(wb + ch * 32);
      float4 wf[8];
      #pragma unroll
      for (int i = 0; i < 8; ++i) wf[i] = wp[i];
      #pragma unroll
      for (int ri = 0; ri < 8; ++ri) {
        const float* xr = &t1s[ri][h * 64 + ch * 32];
        float ax = 0.f, ay = 0.f, az = 0.f, aw = 0.f;
        #pragma unroll
        for (int i = 0; i < 8; ++i) {
          float4 x = *(const float4*)&xr[i * 4];
          ax = fmaf(x.x, wf[i].x, ax); ay = fmaf(x.y, wf[i].y, ay);
          az = fmaf(x.z, wf[i].z, az); aw = fmaf(x.w, wf[i].w, aw);
        }
        accs[ri] += (ax + ay) + (az + aw);
      }
    }
    const float bias = robb[c];
    const float qwc  = qw[c];
    #pragma unroll
    for (int ri = 0; ri < 8; ++ri) {
      float acc = accs[ri];
      acc += __shfl_xor(acc, 32);
      float ctx = fmaxf(acc + bias, 0.f);
      float p = (h == 0) ? qwc * ctx : 0.f;
      p += __shfl_xor(p, 1);  p += __shfl_xor(p, 2);  p += __shfl_xor(p, 4);
      p += __shfl_xor(p, 8);  p += __shfl_xor(p, 16); p += __shfl_xor(p, 32);
      if ((t & 63) == 0) qpart[ri][t >> 6] = p;
    }
  }
  __syncthreads();

  if (t < 8) {
    float qv = (qpart[t][0] + qpart[t][1]) + (qpart[t][2] + qpart[t][3]) + qb[0];
    int r = r0 + t;
    if (r < 768) ws[OFF_QVE + r] = qv;
    else         ws[OFF_QVA + (r - 768)] = qv;
  }
}

// ================================================================
// K8: q_values[b,i] = qv_e[b,i] + sum_j qv_a
// ================================================================
__global__ __launch_bounds__(256) void k8_final(const float* __restrict__ ws, float* __restrict__ out)
{
  const int idx = blockIdx.x * 256 + threadIdx.x;
  if (idx >= 768) return;
  const int b = idx >> 4, i = idx & 15;
  float acc = ws[OFF_QVE + idx];
  const float* qva = ws + OFF_QVA;
  #pragma unroll
  for (int j = 1; j <= 15; ++j) {
    int s = (i >= j) ? 0 : 1;
    acc += qva[(j - 1) * 96 + b * 2 + s];
  }
  out[OUT_QV + idx] = acc;
}

// ================================================================
extern "C" void kernel_launch(void* const* d_in, const int* in_sizes, int n_in,
                              void* d_out, int out_size, void* d_ws, size_t ws_size,
                              hipStream_t stream)
{
  (void)in_sizes; (void)n_in; (void)out_size;
  if (ws_size < (size_t)WS_FLOATS * 4) return;

  const float* obs = (const float*)d_in[0];
  const float* aw1 = (const float*)d_in[1];
  const float* ab1 = (const float*)d_in[2];
  const float* aw2 = (const float*)d_in[3];
  const float* ab2 = (const float*)d_in[4];
  const float* aw3 = (const float*)d_in[5];
  const float* ab3 = (const float*)d_in[6];
  const float* eow = (const float*)d_in[7];
  const float* eob = (const float*)d_in[8];
  const float* eaw = (const float*)d_in[9];
  const float* eab = (const float*)d_in[10];
  const float* riw = (const float*)d_in[11];
  const float* rib = (const float*)d_in[12];
  const float* roww= (const float*)d_in[13];
  const float* robb= (const float*)d_in[14];
  const float* miw = (const float*)d_in[15];
  const float* mib = (const float*)d_in[16];
  const float* mow = (const float*)d_in[17];
  const float* mob = (const float*)d_in[18];
  const float* qw  = (const float*)d_in[19];
  const float* qb  = (const float*)d_in[20];

  float* out = (float*)d_out;
  float* ws  = (float*)d_ws;

  k12ws_front<<<dim3(768), dim3(256), 0, stream>>>(obs, aw1, ab1, aw2, ab2, aw3, ab3,
                                                   eow, eob, eaw, eab, riw, rib, miw, mib,
                                                   out, ws);
  k356_attn<<<dim3(888), dim3(256), 0, stream>>>(ws);
  k7ab_epi<<<dim3(276), dim3(256), 0, stream>>>(mow, mob, roww, robb, qw, qb, ws);
  k8_final<<<dim3(3), dim3(256), 0, stream>>>(ws, out);
}

// Round 17
// 172.391 us; speedup vs baseline: 1.0702x; 1.0702x over previous
//
#include <hip/hip_runtime.h>
#include <math.h>

static __device__ __forceinline__ float lrelu(float x){ return x > 0.f ? x : 0.01f * x; }

// ---- workspace layout (float offsets) ----
#define OFF_XE    196608
#define OFF_XA    294912
#define OFF_QKVE  393216
#define OFF_QKVA  688128
#define OFF_AOP   983040    // 4 splits * 768*128
#define OFF_DEN   1376256   // 4 splits * 768*4
#define OFF_AOA   1388544   // 15*96*128
#define OFF_QVE   1572864
#define OFF_QVA   1573632
#define WS_FLOATS 1575072

// ---- output layout (fp32 elems) ----
#define OUT_POL 0
#define OUT_QV  24576
#define OUT_EO  25344

#define SCALE_ATTN 0.17677669529663689f  // 1/sqrt(32)

// Runtime-looped chunked dot, 4 rows: one 8-float4 weight chunk live at a
// time (#pragma unroll 1 defeats load hoisting — r13/r14 spill lesson).
// 4 rows/block is the measured optimum (r15: 39.8us; 2 rows r16: 50.6us —
// halving rows doubles chip-wide weight traffic; phases are weight-stream
// bound).
template<int NCHUNK>
static __device__ __forceinline__ void phase_dot(
    const float* __restrict__ wbase,
    const float* __restrict__ x0, const float* __restrict__ x1,
    const float* __restrict__ x2, const float* __restrict__ x3,
    float* __restrict__ accs)
{
  #pragma unroll 1
  for (int ch = 0; ch < NCHUNK; ++ch) {
    const float4* wp = (const float4*)(wbase + ch * 32);
    float4 wf[8];
    #pragma unroll
    for (int i = 0; i < 8; ++i) wf[i] = wp[i];
    const float* xr0 = x0 + ch * 32;
    const float* xr1 = x1 + ch * 32;
    const float* xr2 = x2 + ch * 32;
    const float* xr3 = x3 + ch * 32;
    #pragma unroll
    for (int r = 0; r < 4; ++r) {
      const float* xr = (r == 0) ? xr0 : (r == 1) ? xr1 : (r == 2) ? xr2 : xr3;
      float ax = 0.f, ay = 0.f, az = 0.f, aw = 0.f;
      #pragma unroll
      for (int i = 0; i < 8; ++i) {
        float4 x = *(const float4*)&xr[i * 4];
        ax = fmaf(x.x, wf[i].x, ax); ay = fmaf(x.y, wf[i].y, ay);
        az = fmaf(x.z, wf[i].z, az); aw = fmaf(x.w, wf[i].w, aw);
      }
      accs[r] += (ax + ay) + (az + aw);
    }
  }
}

// 4-float4 remainder chunk (for K=160's 16-float tail)
static __device__ __forceinline__ void tail_mac4(const float4* __restrict__ wp,
    const float* __restrict__ x0, const float* __restrict__ x1,
    const float* __restrict__ x2, const float* __restrict__ x3,
    float* __restrict__ accs)
{
  float4 wf[4];
  #pragma unroll
  for (int i = 0; i < 4; ++i) wf[i] = wp[i];
  #pragma unroll
  for (int r = 0; r < 4; ++r) {
    const float* xr = (r == 0) ? x0 : (r == 1) ? x1 : (r == 2) ? x2 : x3;
    float ax = 0.f, ay = 0.f, az = 0.f, aw = 0.f;
    #pragma unroll
    for (int i = 0; i < 4; ++i) {
      float4 x = *(const float4*)&xr[i * 4];
      ax = fmaf(x.x, wf[i].x, ax); ay = fmaf(x.y, wf[i].y, ay);
      az = fmaf(x.z, wf[i].z, az); aw = fmaf(x.w, wf[i].w, aw);
    }
    accs[r] += (ax + ay) + (az + aw);
  }
}

// ================================================================
// K12ws (r15 exact): weight-stationary front end, 4 rows/block, grid 384.
// Blocks 0..191   (E): obs -> eo -> x_e -> qkv_e
// Blocks 192..383 (A): obs -> L1 -> L2 -> L3/pol -> ea -> x_a -> qkv_a
// ================================================================
__global__ __launch_bounds__(256) void k12ws_front(
    const float* __restrict__ obs,
    const float* __restrict__ aw1, const float* __restrict__ ab1,
    const float* __restrict__ aw2, const float* __restrict__ ab2,
    const float* __restrict__ aw3, const float* __restrict__ ab3,
    const float* __restrict__ eow, const float* __restrict__ eob,
    const float* __restrict__ eaw, const float* __restrict__ eab,
    const float* __restrict__ riw, const float* __restrict__ rib,
    const float* __restrict__ miw, const float* __restrict__ mib,
    float* __restrict__ out, float* __restrict__ ws)
{
  __shared__ float sA[4][256];   // A: h1, then ea in [0..128)  | E: eo
  __shared__ float sB[4][160];   // A: [obs | pol]              | E: obs
  __shared__ float sC[4][128];   // A: h2, then x_a             | E: x_e
  const int t  = threadIdx.x;
  const int bx = blockIdx.x;
  const bool isE = (bx < 192);
  const int r0 = (isE ? bx : bx - 192) * 4;

  const int c = (t & 31) | ((t >> 6) << 5);   // out-col 0..127
  const int h = (t >> 5) & 1;                 // k-half

  for (int s = t; s < 512; s += 256) {
    int ri = s >> 7, k = s & 127;
    sB[ri][k] = obs[(r0 + ri) * 128 + k];
  }
  __syncthreads();

  if (isE) {
    { // ---- eo ----
      float accs[4] = {0.f, 0.f, 0.f, 0.f};
      phase_dot<2>(eow + c * 128 + h * 64,
                   &sB[0][h*64], &sB[1][h*64], &sB[2][h*64], &sB[3][h*64], accs);
      const float bias = eob[c];
      #pragma unroll
      for (int r = 0; r < 4; ++r) {
        float acc = accs[r];
        acc += __shfl_xor(acc, 32);
        if (h == 0) {
          float v = acc + bias;
          sA[r][c] = v;
          out[OUT_EO + (r0 + r) * 128 + c] = v;
        }
      }
    }
    __syncthreads();
    { // ---- x_e ----
      float accs[4] = {0.f, 0.f, 0.f, 0.f};
      phase_dot<2>(riw + c * 128 + h * 64,
                   &sA[0][h*64], &sA[1][h*64], &sA[2][h*64], &sA[3][h*64], accs);
      const float bias = rib[c];
      #pragma unroll
      for (int r = 0; r < 4; ++r) {
        float acc = accs[r];
        acc += __shfl_xor(acc, 32);
        if (h == 0) {
          float v = fmaxf(acc + bias, 0.f);
          sC[r][c] = v;
          ws[OFF_XE + (r0 + r) * 128 + c] = v;
        }
      }
    }
    __syncthreads();
    // ---- qkv_e (3 col-groups) ----
    #pragma unroll 1
    for (int g = 0; g < 3; ++g) {
      float accs[4] = {0.f, 0.f, 0.f, 0.f};
      phase_dot<2>(miw + (size_t)(g * 128 + c) * 128 + h * 64,
                   &sC[0][h*64], &sC[1][h*64], &sC[2][h*64], &sC[3][h*64], accs);
      const float bias = mib[g * 128 + c];
      #pragma unroll
      for (int r = 0; r < 4; ++r) {
        float acc = accs[r];
        acc += __shfl_xor(acc, 32);
        if (h == 0)
          ws[OFF_QKVE + (size_t)(r0 + r) * 384 + g * 128 + c] = acc + bias;
      }
    }
  } else {
    // ---- L1 (2 col-groups) ----
    #pragma unroll 1
    for (int g = 0; g < 2; ++g) {
      float accs[4] = {0.f, 0.f, 0.f, 0.f};
      phase_dot<2>(aw1 + (size_t)(g * 128 + c) * 128 + h * 64,
                   &sB[0][h*64], &sB[1][h*64], &sB[2][h*64], &sB[3][h*64], accs);
      const float bias = ab1[g * 128 + c];
      #pragma unroll
      for (int r = 0; r < 4; ++r) {
        float acc = accs[r];
        acc += __shfl_xor(acc, 32);
        if (h == 0) sA[r][g * 128 + c] = lrelu(acc + bias);
      }
    }
    __syncthreads();
    { // ---- L2 (K=256: two 128-halves) ----
      float accs[4] = {0.f, 0.f, 0.f, 0.f};
      phase_dot<2>(aw2 + (size_t)c * 256 + h * 64,
                   &sA[0][h*64], &sA[1][h*64], &sA[2][h*64], &sA[3][h*64], accs);
      phase_dot<2>(aw2 + (size_t)c * 256 + 128 + h * 64,
                   &sA[0][128+h*64], &sA[1][128+h*64], &sA[2][128+h*64], &sA[3][128+h*64], accs);
      const float bias = ab2[c];
      #pragma unroll
      for (int r = 0; r < 4; ++r) {
        float acc = accs[r];
        acc += __shfl_xor(acc, 32);
        if (h == 0) sC[r][c] = lrelu(acc + bias);
      }
    }
    __syncthreads();
    // ---- L3 + GELU (wave 0 only) ----
    if (t < 64) {
      const int c2 = t & 31, h2 = t >> 5;
      float accs[4] = {0.f, 0.f, 0.f, 0.f};
      phase_dot<2>(aw3 + (size_t)c2 * 128 + h2 * 64,
                   &sC[0][h2*64], &sC[1][h2*64], &sC[2][h2*64], &sC[3][h2*64], accs);
      const float bias = ab3[c2];
      #pragma unroll
      for (int r = 0; r < 4; ++r) {
        float acc = accs[r];
        acc += __shfl_xor(acc, 32);
        if (h2 == 0) {
          float a = acc + bias;
          float g = 0.5f * a * (1.f + erff(a * 0.70710678118654752f));
          sB[r][128 + c2] = g;
          out[OUT_POL + (r0 + r) * 32 + c2] = g;
        }
      }
    }
    __syncthreads();
    { // ---- ea (K=160: halves of 80 = 2 chunks + 16-float tail) ----
      float accs[4] = {0.f, 0.f, 0.f, 0.f};
      const float* wb = eaw + (size_t)c * 160 + h * 80;
      phase_dot<2>(wb, &sB[0][h*80], &sB[1][h*80], &sB[2][h*80], &sB[3][h*80], accs);
      tail_mac4((const float4*)(wb + 64),
                &sB[0][h*80+64], &sB[1][h*80+64], &sB[2][h*80+64], &sB[3][h*80+64], accs);
      const float bias = eab[c];
      #pragma unroll
      for (int r = 0; r < 4; ++r) {
        float acc = accs[r];
        acc += __shfl_xor(acc, 32);
        if (h == 0) sA[r][c] = acc + bias;
      }
    }
    __syncthreads();
    { // ---- x_a ----
      float accs[4] = {0.f, 0.f, 0.f, 0.f};
      phase_dot<2>(riw + c * 128 + h * 64,
                   &sA[0][h*64], &sA[1][h*64], &sA[2][h*64], &sA[3][h*64], accs);
      const float bias = rib[c];
      #pragma unroll
      for (int r = 0; r < 4; ++r) {
        float acc = accs[r];
        acc += __shfl_xor(acc, 32);
        if (h == 0) {
          float v = fmaxf(acc + bias, 0.f);
          sC[r][c] = v;
          ws[OFF_XA + (r0 + r) * 128 + c] = v;
        }
      }
    }
    __syncthreads();
    // ---- qkv_a (3 col-groups) ----
    #pragma unroll 1
    for (int g = 0; g < 3; ++g) {
      float accs[4] = {0.f, 0.f, 0.f, 0.f};
      phase_dot<2>(miw + (size_t)(g * 128 + c) * 128 + h * 64,
                   &sC[0][h*64], &sC[1][h*64], &sC[2][h*64], &sC[3][h*64], accs);
      const float bias = mib[g * 128 + c];
      #pragma unroll
      for (int r = 0; r < 4; ++r) {
        float acc = accs[r];
        acc += __shfl_xor(acc, 32);
        if (h == 0)
          ws[OFF_QKVA + (size_t)(r0 + r) * 384 + g * 128 + c] = acc + bias;
      }
    }
  }
}

// ================================================================
// K356: fused attention (unchanged).
// ================================================================
__global__ __launch_bounds__(256) void k356_attn(float* __restrict__ ws)
{
  __shared__ __align__(16) union {
    struct { float Qs[16 * 36]; float KsT[32 * 68]; float VsT[32 * 68]; float Ss[16 * 68]; } e;
    struct { float Qb[48 * 33]; float Ka[96 * 33]; float Va[96 * 36]; float Ss[48 * 97]; float rinv[48]; } a;
  } su;
  const int t  = threadIdx.x;
  const int bx = blockIdx.x;

  if (bx < 768) {
    const int l0 = (bx % 48) * 16, h = (bx / 48) & 3, sp = bx / 192;
    const float* qkve = ws + OFF_QKVE;

    for (int f = t; f < 512; f += 256)
      su.e.Qs[(f >> 5) * 36 + (f & 31)] = qkve[(size_t)(l0 + (f >> 5)) * 384 + h * 32 + (f & 31)];
    __syncthreads();

    const int l = t >> 4, j = t & 15, c0 = j * 4;
    float q[32];
    #pragma unroll
    for (int dd = 0; dd < 8; ++dd) {
      float4 qq = *(const float4*)&su.e.Qs[l * 36 + dd * 4];
      q[dd*4+0] = qq.x; q[dd*4+1] = qq.y; q[dd*4+2] = qq.z; q[dd*4+3] = qq.w;
    }
    float o0 = 0.f, o1 = 0.f, dsum = 0.f;

    for (int mt = sp * 3; mt < sp * 3 + 3; ++mt) {
      const int m0 = mt * 64;
      __syncthreads();
      for (int f = t; f < 2048; f += 256) {
        int i = f >> 5, d = f & 31;
        const float* src = qkve + (size_t)(m0 + i) * 384 + h * 32 + d;
        su.e.KsT[d * 68 + i] = src[128];
        su.e.VsT[d * 68 + i] = src[256];
      }
      __syncthreads();

      float s0 = 0.f, s1 = 0.f, s2 = 0.f, s3 = 0.f;
      #pragma unroll
      for (int d = 0; d < 32; ++d) {
        float4 kk = *(const float4*)&su.e.KsT[d * 68 + c0];
        s0 = fmaf(q[d], kk.x, s0); s1 = fmaf(q[d], kk.y, s1);
        s2 = fmaf(q[d], kk.z, s2); s3 = fmaf(q[d], kk.w, s3);
      }
      s0 = expf(s0 * SCALE_ATTN); s1 = expf(s1 * SCALE_ATTN);
      s2 = expf(s2 * SCALE_ATTN); s3 = expf(s3 * SCALE_ATTN);
      float4 sv; sv.x = s0; sv.y = s1; sv.z = s2; sv.w = s3;
      *(float4*)&su.e.Ss[l * 68 + c0] = sv;
      float psum = (s0 + s1) + (s2 + s3);
      psum += __shfl_xor(psum, 1); psum += __shfl_xor(psum, 2);
      psum += __shfl_xor(psum, 4); psum += __shfl_xor(psum, 8);
      dsum += psum;

      float t0x=0.f,t0y=0.f,t0z=0.f,t0w=0.f, t1x=0.f,t1y=0.f,t1z=0.f,t1w=0.f;
      #pragma unroll
      for (int k4 = 0; k4 < 16; ++k4) {
        float4 p  = *(const float4*)&su.e.Ss[l * 68 + k4 * 4];
        float4 va = *(const float4*)&su.e.VsT[j * 68 + k4 * 4];
        float4 vb = *(const float4*)&su.e.VsT[(j + 16) * 68 + k4 * 4];
        t0x = fmaf(p.x, va.x, t0x); t0y = fmaf(p.y, va.y, t0y);
        t0z = fmaf(p.z, va.z, t0z); t0w = fmaf(p.w, va.w, t0w);
        t1x = fmaf(p.x, vb.x, t1x); t1y = fmaf(p.y, vb.y, t1y);
        t1z = fmaf(p.z, vb.z, t1z); t1w = fmaf(p.w, vb.w, t1w);
      }
      o0 += (t0x + t0y) + (t0z + t0w);
      o1 += (t1x + t1y) + (t1z + t1w);
    }

    float* aop = ws + OFF_AOP + (size_t)sp * 98304;
    aop[(size_t)(l0 + l) * 128 + h * 32 + j]      = o0;
    aop[(size_t)(l0 + l) * 128 + h * 32 + j + 16] = o1;
    if (j == 0) ws[OFF_DEN + sp * 3072 + (l0 + l) * 4 + h] = dsum;
  } else {
    const int z  = bx - 768;
    const int j1 = z >> 3;
    const int h  = (z & 7) >> 1, rb = z & 1;
    const int jj = j1 + 1;
    const float* qkva = ws + OFF_QKVA;

    for (int f = t; f < 3072; f += 256) {
      int ml = f >> 5, d = f & 31;
      int bp = ml >> 1, spar = ml & 1;
      int ag = spar ? jj : (jj - 1);
      const float* src = qkva + (size_t)(bp * 16 + ag) * 384 + h * 32 + d;
      su.a.Ka[ml * 33 + d] = src[128];
      su.a.Va[ml * 36 + d] = src[256];
    }
    for (int f = t; f < 1536; f += 256) {
      int ql = f >> 5, d = f & 31;
      int Lb = rb * 48 + ql;
      int b = Lb >> 1, s = Lb & 1;
      int ag = s ? jj : (jj - 1);
      su.a.Qb[ql * 33 + d] = qkva[(size_t)(b * 16 + ag) * 384 + h * 32 + d];
    }
    __syncthreads();

    {
      const int tl = (t >> 4) * 3, tm = (t & 15) * 6;
      float acc[3][6] = {{0.f}};
      #pragma unroll
      for (int d = 0; d < 32; ++d) {
        float qv[3], kv[6];
        #pragma unroll
        for (int r = 0; r < 3; ++r) qv[r] = su.a.Qb[(tl + r) * 33 + d];
        #pragma unroll
        for (int c = 0; c < 6; ++c) kv[c] = su.a.Ka[(tm + c) * 33 + d];
        #pragma unroll
        for (int r = 0; r < 3; ++r)
          #pragma unroll
          for (int c = 0; c < 6; ++c) acc[r][c] = fmaf(qv[r], kv[c], acc[r][c]);
      }
      const float wj = (float)jj, wnj = (float)(16 - jj);
      float rs[3] = {0.f, 0.f, 0.f};
      #pragma unroll
      for (int r = 0; r < 3; ++r)
        #pragma unroll
        for (int c = 0; c < 6; ++c) {
          float w = ((tm + c) & 1) ? wj : wnj;
          float p = w * expf(acc[r][c] * SCALE_ATTN);
          su.a.Ss[(tl + r) * 97 + tm + c] = p;
          rs[r] += p;
        }
      #pragma unroll
      for (int r = 0; r < 3; ++r) {
        rs[r] += __shfl_xor(rs[r], 1); rs[r] += __shfl_xor(rs[r], 2);
        rs[r] += __shfl_xor(rs[r], 4); rs[r] += __shfl_xor(rs[r], 8);
      }
      if ((t & 15) == 0) {
        su.a.rinv[tl + 0] = 1.f / rs[0];
        su.a.rinv[tl + 1] = 1.f / rs[1];
        su.a.rinv[tl + 2] = 1.f / rs[2];
      }
    }
    __syncthreads();

    if (t < 192) {
      const int l0 = (t >> 3) * 2, d0 = (t & 7) * 4;
      float a0x=0.f,a0y=0.f,a0z=0.f,a0w=0.f, a1x=0.f,a1y=0.f,a1z=0.f,a1w=0.f;
      for (int m = 0; m < 96; ++m) {
        float p0 = su.a.Ss[l0 * 97 + m], p1 = su.a.Ss[(l0 + 1) * 97 + m];
        float4 v = *(const float4*)&su.a.Va[m * 36 + d0];
        a0x = fmaf(p0, v.x, a0x); a0y = fmaf(p0, v.y, a0y);
        a0z = fmaf(p0, v.z, a0z); a0w = fmaf(p0, v.w, a0w);
        a1x = fmaf(p1, v.x, a1x); a1y = fmaf(p1, v.y, a1y);
        a1z = fmaf(p1, v.z, a1z); a1w = fmaf(p1, v.w, a1w);
      }
      const float s0 = su.a.rinv[l0], s1 = su.a.rinv[l0 + 1];
      float* ao = ws + OFF_AOA + (size_t)(j1 * 96 + rb * 48 + l0) * 128 + h * 32 + d0;
      float4 o0; o0.x = a0x * s0; o0.y = a0y * s0; o0.z = a0z * s0; o0.w = a0w * s0;
      float4 o1; o1.x = a1x * s1; o1.y = a1y * s1; o1.z = a1z * s1; o1.w = a1w * s1;
      *(float4*)ao = o0;
      *(float4*)(ao + 128) = o1;
    }
  }
}

// ================================================================
// K7ab: merged epilogue (kept from r16). Per 8 ctx rows: ao (+k-split
// combine for e-rows) -> t1 in LDS -> ctx -> qv. grid=276.
// ================================================================
__global__ __launch_bounds__(256) void k7ab_epi(
    const float* __restrict__ mow, const float* __restrict__ mob,
    const float* __restrict__ roww, const float* __restrict__ robb,
    const float* __restrict__ qw,  const float* __restrict__ qb,
    float* __restrict__ ws)
{
  __shared__ float rows_in[8][132];
  __shared__ float res[8][132];
  __shared__ float t1s[8][132];
  __shared__ float qpart[8][4];
  const int t  = threadIdx.x;
  const int r0 = blockIdx.x * 8;

  for (int s = t; s < 1024; s += 256) {
    int ri = s >> 7, c = s & 127;
    int r = r0 + ri;
    float aoval, x1v;
    if (r < 768) {
      float num = ws[OFF_AOP + 0*98304 + (size_t)r*128 + c]
                + ws[OFF_AOP + 1*98304 + (size_t)r*128 + c]
                + ws[OFF_AOP + 2*98304 + (size_t)r*128 + c]
                + ws[OFF_AOP + 3*98304 + (size_t)r*128 + c];
      int hh = c >> 5;
      float den = ws[OFF_DEN + 0*3072 + r*4 + hh] + ws[OFF_DEN + 1*3072 + r*4 + hh]
                + ws[OFF_DEN + 2*3072 + r*4 + hh] + ws[OFF_DEN + 3*3072 + r*4 + hh];
      aoval = num / den;
      x1v = ws[OFF_XE + r*128 + c];
    } else {
      int rr = r - 768;
      aoval = ws[OFF_AOA + (size_t)rr*128 + c];
      int jx = rr / 96, l96 = rr % 96;
      int b = l96 >> 1, sa = l96 & 1;
      int ag = sa ? (jx + 1) : jx;
      x1v = ws[OFF_XA + (b*16 + ag)*128 + c];
    }
    rows_in[ri][c] = aoval;
    res[ri][c] = x1v;
  }

  const int c = (t & 31) | ((t >> 6) << 5);
  const int h = (t >> 5) & 1;
  __syncthreads();

  { // t1 phase (runtime-looped chunks)
    float accs[8] = {0.f,0.f,0.f,0.f,0.f,0.f,0.f,0.f};
    const float* wb = mow + c * 128 + h * 64;
    #pragma unroll 1
    for (int ch = 0; ch < 2; ++ch) {
      const float4* wp = (const float4*)(wb + ch * 32);
      float4 wf[8];
      #pragma unroll
      for (int i = 0; i < 8; ++i) wf[i] = wp[i];
      #pragma unroll
      for (int ri = 0; ri < 8; ++ri) {
        const float* xr = &rows_in[ri][h * 64 + ch * 32];
        float ax = 0.f, ay = 0.f, az = 0.f, aw = 0.f;
        #pragma unroll
        for (int i = 0; i < 8; ++i) {
          float4 x = *(const float4*)&xr[i * 4];
          ax = fmaf(x.x, wf[i].x, ax); ay = fmaf(x.y, wf[i].y, ay);
          az = fmaf(x.z, wf[i].z, az); aw = fmaf(x.w, wf[i].w, aw);
        }
        accs[ri] += (ax + ay) + (az + aw);
      }
    }
    const float bias = mob[c];
    #pragma unroll
    for (int ri = 0; ri < 8; ++ri) {
      float acc = accs[ri];
      acc += __shfl_xor(acc, 32);
      if (h == 0) t1s[ri][c] = acc + bias + res[ri][c];
    }
  }
  __syncthreads();

  { // ctx + qv phase
    float accs[8] = {0.f,0.f,0.f,0.f,0.f,0.f,0.f,0.f};
    const float* wb = roww + c * 128 + h * 64;
    #pragma unroll 1
    for (int ch = 0; ch < 2; ++ch) {
      const float4* wp = (const float4*)(wb + ch * 32);
      float4 wf[8];
      #pragma unroll
      for (int i = 0; i < 8; ++i) wf[i] = wp[i];
      #pragma unroll
      for (int ri = 0; ri < 8; ++ri) {
        const float* xr = &t1s[ri][h * 64 + ch * 32];
        float ax = 0.f, ay = 0.f, az = 0.f, aw = 0.f;
        #pragma unroll
        for (int i = 0; i < 8; ++i) {
          float4 x = *(const float4*)&xr[i * 4];
          ax = fmaf(x.x, wf[i].x, ax); ay = fmaf(x.y, wf[i].y, ay);
          az = fmaf(x.z, wf[i].z, az); aw = fmaf(x.w, wf[i].w, aw);
        }
        accs[ri] += (ax + ay) + (az + aw);
      }
    }
    const float bias = robb[c];
    const float qwc  = qw[c];
    #pragma unroll
    for (int ri = 0; ri < 8; ++ri) {
      float acc = accs[ri];
      acc += __shfl_xor(acc, 32);
      float ctx = fmaxf(acc + bias, 0.f);
      float p = (h == 0) ? qwc * ctx : 0.f;
      p += __shfl_xor(p, 1);  p += __shfl_xor(p, 2);  p += __shfl_xor(p, 4);
      p += __shfl_xor(p, 8);  p += __shfl_xor(p, 16); p += __shfl_xor(p, 32);
      if ((t & 63) == 0) qpart[ri][t >> 6] = p;
    }
  }
  __syncthreads();

  if (t < 8) {
    float qv = (qpart[t][0] + qpart[t][1]) + (qpart[t][2] + qpart[t][3]) + qb[0];
    int r = r0 + t;
    if (r < 768) ws[OFF_QVE + r] = qv;
    else         ws[OFF_QVA + (r - 768)] = qv;
  }
}

// ================================================================
// K8: q_values[b,i] = qv_e[b,i] + sum_j qv_a
// ================================================================
__global__ __launch_bounds__(256) void k8_final(const float* __restrict__ ws, float* __restrict__ out)
{
  const int idx = blockIdx.x * 256 + threadIdx.x;
  if (idx >= 768) return;
  const int b = idx >> 4, i = idx & 15;
  float acc = ws[OFF_QVE + idx];
  const float* qva = ws + OFF_QVA;
  #pragma unroll
  for (int j = 1; j <= 15; ++j) {
    int s = (i >= j) ? 0 : 1;
    acc += qva[(j - 1) * 96 + b * 2 + s];
  }
  out[OUT_QV + idx] = acc;
}

// ================================================================
extern "C" void kernel_launch(void* const* d_in, const int* in_sizes, int n_in,
                              void* d_out, int out_size, void* d_ws, size_t ws_size,
                              hipStream_t stream)
{
  (void)in_sizes; (void)n_in; (void)out_size;
  if (ws_size < (size_t)WS_FLOATS * 4) return;

  const float* obs = (const float*)d_in[0];
  const float* aw1 = (const float*)d_in[1];
  const float* ab1 = (const float*)d_in[2];
  const float* aw2 = (const float*)d_in[3];
  const float* ab2 = (const float*)d_in[4];
  const float* aw3 = (const float*)d_in[5];
  const float* ab3 = (const float*)d_in[6];
  const float* eow = (const float*)d_in[7];
  const float* eob = (const float*)d_in[8];
  const float* eaw = (const float*)d_in[9];
  const float* eab = (const float*)d_in[10];
  const float* riw = (const float*)d_in[11];
  const float* rib = (const float*)d_in[12];
  const float* roww= (const float*)d_in[13];
  const float* robb= (const float*)d_in[14];
  const float* miw = (const float*)d_in[15];
  const float* mib = (const float*)d_in[16];
  const float* mow = (const float*)d_in[17];
  const float* mob = (const float*)d_in[18];
  const float* qw  = (const float*)d_in[19];
  const float* qb  = (const float*)d_in[20];

  float* out = (float*)d_out;
  float* ws  = (float*)d_ws;

  k12ws_front<<<dim3(384), dim3(256), 0, stream>>>(obs, aw1, ab1, aw2, ab2, aw3, ab3,
                                                   eow, eob, eaw, eab, riw, rib, miw, mib,
                                                   out, ws);
  k356_attn<<<dim3(888), dim3(256), 0, stream>>>(ws);
  k7ab_epi<<<dim3(276), dim3(256), 0, stream>>>(mow, mob, roww, robb, qw, qb, ws);
  k8_final<<<dim3(3), dim3(256), 0, stream>>>(ws, out);
}